// Round 14
// baseline (15132.219 us; speedup 1.0000x reference)
//
#include <hip/hip_runtime.h>
#include <hip/hip_bf16.h>

#define N_LAYERS 1000
#define DD 100
#define DOUT 10
#define TM 64
#define ROWB 264                  // act row stride bytes: 66 words = 2 mod 32 -> 2-way banks (free)
#define PLANE (TM * ROWB)         // 16896 B = one act buffer (single bf16 plane)
#define SMEM_BYTES (2 * PLANE)    // double-buffered: 33792 B -> 4 wgs/CU
#define ROW32 (32 * ROWB)         // 8448: +1 m-tile offset, compile-time immediate
#define LCHUNK 14336              // packed W bytes per (layer, group)
#define LSTRIDE (2 * LCHUNK)      // 28672 B per layer
#define POFF_MAX ((size_t)(N_LAYERS - 1) * LSTRIDE + 6 * 2048)   // last valid fragment offset

typedef short s4v __attribute__((ext_vector_type(4)));
typedef short s8v __attribute__((ext_vector_type(8)));
typedef float f16v __attribute__((ext_vector_type(16)));

__device__ __forceinline__ unsigned short f2bf(float f) {
  __hip_bfloat16 h = __float2bfloat16(f);   // HW RNE
  return *reinterpret_cast<unsigned short*>(&h);
}
__device__ __forceinline__ float bf2f(unsigned short h) {
  return __uint_as_float(((unsigned)h) << 16);
}

// ---------------- prologue: W (f32) + bias -> lane-packed bf16 fragments (hi only) ----------
// byte off = (L*2+g)*LCHUNK + ks*2048 + f*1024 + lane*16
// frag: n = g*64+f*32+(lane&31), k = ks*16+(lane>>5)*8+j ; k==100 holds bias; pads zero.
__global__ __launch_bounds__(256)
void presplit_kernel(const float* __restrict__ W, const float* __restrict__ b,
                     char* __restrict__ hi_g) {
  int idx = blockIdx.x * 256 + threadIdx.x;
  if (idx >= N_LAYERS * 2 * 7 * 2 * 64) return;
  int lane = idx & 63;
  int f = (idx >> 6) & 1;
  int r = idx >> 7;
  int ks = r % 7;
  int q = r / 7;
  int g = q & 1;
  int L = q >> 1;
  int n = g * 64 + f * 32 + (lane & 31);
  int k0 = ks * 16 + (lane >> 5) * 8;
  s8v hv;
#pragma unroll
  for (int j = 0; j < 8; ++j) {
    int k = k0 + j;
    float v = 0.0f;
    if (n < DD) {
      if (k < DD) v = W[((size_t)L * DD + n) * DD + k];
      else if (k == DD) v = b[(size_t)L * DD + n];
    }
    hv[j] = (short)f2bf(v);
  }
  *(s8v*)(hi_g + (size_t)idx * 16) = hv;
}

// fallback W gather from raw f32 (one 32-channel fragment; used when d_ws too small)
__device__ __forceinline__ void wload_f32(s8v& h, int L, int ks, int nb,
                                          int l31, int lhi,
                                          const float* __restrict__ W_g,
                                          const float* __restrict__ b_g) {
  int n = nb + l31;
  int k0 = ks * 16 + lhi * 8;
  s8v hv;
#pragma unroll
  for (int j = 0; j < 8; ++j) {
    int k = k0 + j;
    float v = 0.0f;
    if (n < DD) {
      if (k < DD) v = W_g[((size_t)L * DD + n) * DD + k];
      else if (k == DD) v = b_g[(size_t)L * DD + n];
    }
    hv[j] = (short)f2bf(v);
  }
  h = hv;
}

// ---------------- one layer, phase P of 4 (static W-slot indices, depth-4 pipeline) ---------
// Fragment stream t = 7L+ks lives in slot t&3 (L === P mod 4, 7 === 3 mod 4 -> slot =
// (3P+ks)&3). Consume then refill with fragment t+4. poff advance: +2048 in-layer,
// +16384 across the boundary (r9/r13-verified algebra).
template <int PRE, int P>
__device__ __forceinline__ void layer_step(
    int L, const char* __restrict__ rb, char* __restrict__ wb,
    int nb, int l31, int lhi,
    const char* __restrict__ pH, size_t& poff,
    s8v (&wh)[4], f16v (&xr)[2], const f16v& zro,
    const float* __restrict__ W_g, const float* __restrict__ b_g) {
  f16v acc[2];
#pragma unroll
  for (int ks = 0; ks < 7; ++ks) {
    const int s = (3 * P + ks) & 3;
    s4v a0 = *(const s4v*)(rb + ks * 32);
    s4v a1 = *(const s4v*)(rb + ks * 32 + 8);
    s4v b0 = *(const s4v*)(rb + ROW32 + ks * 32);
    s4v b1 = *(const s4v*)(rb + ROW32 + ks * 32 + 8);
    s8v ah0 = __builtin_shufflevector(a0, a1, 0, 1, 2, 3, 4, 5, 6, 7);
    s8v ah1 = __builtin_shufflevector(b0, b1, 0, 1, 2, 3, 4, 5, 6, 7);
    if (ks == 0) {
      acc[0] = __builtin_amdgcn_mfma_f32_32x32x16_bf16(wh[s], ah0, zro, 0, 0, 0);
      acc[1] = __builtin_amdgcn_mfma_f32_32x32x16_bf16(wh[s], ah1, zro, 0, 0, 0);
    } else {
      acc[0] = __builtin_amdgcn_mfma_f32_32x32x16_bf16(wh[s], ah0, acc[0], 0, 0, 0);
      acc[1] = __builtin_amdgcn_mfma_f32_32x32x16_bf16(wh[s], ah1, acc[1], 0, 0, 0);
    }

    // refill the slot just consumed with fragment t+4 (1 KB: this wave's f-half only)
    const int nks = (ks + 4) % 7;     // static
    if (PRE) {
      if (poff <= POFF_MAX) wh[s] = *(const s8v*)(pH + poff);
      poff += (nks == 6) ? (LSTRIDE - 6 * 2048) : 2048;   // wrap delta = 16384
    } else {
      const int Ln = L + (ks >= 3 ? 1 : 0);
      if (Ln < N_LAYERS) wload_f32(wh[s], Ln, nks, nb, l31, lhi, W_g, b_g);
    }
  }

  // ---- epilogue: relu (+residual at block end), cast bf16, write both m-tiles ----
  const bool bend = ((L % 10) == 9);
#pragma unroll
  for (int mi = 0; mi < 2; ++mi) {
    char* dstm = wb + mi * ROW32;
#pragma unroll
    for (int q = 0; q < 4; ++q) {
      const int n0 = nb + 8 * q + 4 * lhi;
      char* dst = dstm + q * 16;
      if (n0 == 100) {   // bias column: act[100]=1.0, pads 101..103 = 0
        s4v hq;
        hq[0] = (short)0x3F80; hq[1] = 0; hq[2] = 0; hq[3] = 0;
        *(s4v*)dst = hq;
      } else {
        s4v hq;
#pragma unroll
        for (int j = 0; j < 4; ++j) {
          const int r = q * 4 + j;
          float o = fmaxf(acc[mi][r], 0.0f);
          if (bend) { o += xr[mi][r]; xr[mi][r] = o; }   // exact f32 stream carrier
          hq[j] = (short)f2bf(o);
        }
        *(s4v*)dst = hq;
      }
    }
  }
  __syncthreads();   // single barrier per layer (double buffer)
}

// ---------------- main kernel: 1024 wgs x 256 thr, 4 wgs/CU = 16 waves/CU (4/SIMD) --------
// wg = 64 batch rows, 4 waves. Wave wv owns channels [wv*32, wv*32+32) x all 64 rows
// (2 m-tiles): disjoint W f-half fragments -> still zero W duplication per CU.
template <int PRE>
__global__ __launch_bounds__(256, 4)
void resnet_main(const float* __restrict__ x_g,
                 const float* __restrict__ W_g, const float* __restrict__ b_g,
                 const float* __restrict__ Wf_g, const float* __restrict__ bf_g,
                 float* __restrict__ out_g,
                 const char* __restrict__ whi_g) {
  extern __shared__ char smem[];

  const int tid = threadIdx.x;
  const int lane = tid & 63;
  const int wv = tid >> 6;         // wave 0..3
  const int nb = wv * 32;          // wave's channel base
  const int l31 = lane & 31;
  const int lhi = lane >> 5;
  const size_t mbase = (size_t)blockIdx.x * TM;

  // ---- initial activation staging into buf A: bf16(x); k==100 -> 1.0; k>100 -> 0 ----
  for (int idx = tid; idx < TM * 16; idx += 256) {
    int m = idx >> 4, kb = idx & 15;
    s4v h0, h1;
#pragma unroll
    for (int j = 0; j < 8; ++j) {
      int k = kb * 8 + j;
      float v = (k < DD) ? x_g[(mbase + m) * DD + k] : (k == DD ? 1.0f : 0.0f);
      if (j < 4) h0[j] = (short)f2bf(v);
      else       h1[j - 4] = (short)f2bf(v);
    }
    char* p = smem + m * ROWB + kb * 16;
    *(s4v*)p = h0;
    *(s4v*)(p + 8) = h1;
  }

  // ---- residual: block input in f32 registers, C-fragment layout (2 m-tiles) ----
  f16v xr[2];
#pragma unroll
  for (int mi = 0; mi < 2; ++mi)
#pragma unroll
    for (int r = 0; r < 16; ++r) {
      int n = nb + (r & 3) + 8 * (r >> 2) + 4 * lhi;
      xr[mi][r] = (n < DD) ? x_g[(mbase + mi * 32 + l31) * DD + n] : 0.0f;
    }

  f16v zro;
#pragma unroll
  for (int r = 0; r < 16; ++r) zro[r] = 0.0f;

  // ---- depth-4 W register pipeline: preload fragments t=0..3 (layer 0, ks 0..3) ----
  const char* pH = whi_g + (size_t)(wv >> 1) * LCHUNK + (wv & 1) * 1024 + lane * 16;
  s8v wh[4];
  if (PRE) {
#pragma unroll
    for (int s = 0; s < 4; ++s) wh[s] = *(const s8v*)(pH + s * 2048);
  } else {
#pragma unroll
    for (int s = 0; s < 4; ++s) wload_f32(wh[s], 0, s, nb, l31, lhi, W_g, b_g);
  }
  size_t poff = 4 * 2048;   // next fragment to load: t=4 (layer 0, ks 4)

  __syncthreads();

  // buffer A = smem, buffer B = smem + PLANE; layer L reads buf[L&1], writes buf[~L&1]
  const char* rbA = smem + l31 * ROWB + lhi * 16;
  const char* rbB = rbA + PLANE;
  char* wbA = smem + l31 * ROWB + nb * 2 + lhi * 8;
  char* wbB = wbA + PLANE;

  for (int L = 0; L < N_LAYERS; L += 4) {
    layer_step<PRE, 0>(L + 0, rbA, wbB, nb, l31, lhi, pH, poff, wh, xr, zro, W_g, b_g);
    layer_step<PRE, 1>(L + 1, rbB, wbA, nb, l31, lhi, pH, poff, wh, xr, zro, W_g, b_g);
    layer_step<PRE, 2>(L + 2, rbA, wbB, nb, l31, lhi, pH, poff, wh, xr, zro, W_g, b_g);
    layer_step<PRE, 3>(L + 3, rbB, wbA, nb, l31, lhi, pH, poff, wh, xr, zro, W_g, b_g);
  }

  // ---- final projection: out = act @ Wf^T + bf  (act = buf A after layer 999) ----
  if (tid < TM) {
    int m = tid;
    const char* p = smem + m * ROWB;
    float xv[104];
#pragma unroll
    for (int kb = 0; kb < 13; ++kb) {
      s4v h0 = *(const s4v*)(p + kb * 16);
      s4v h1 = *(const s4v*)(p + kb * 16 + 8);
#pragma unroll
      for (int j = 0; j < 4; ++j) {
        xv[kb * 8 + j]     = bf2f((unsigned short)h0[j]);
        xv[kb * 8 + 4 + j] = bf2f((unsigned short)h1[j]);
      }
    }
#pragma unroll
    for (int o = 0; o < DOUT; ++o) {
      float s = bf_g[o];
#pragma unroll
      for (int k = 0; k < DD; ++k) s += xv[k] * Wf_g[o * DD + k];
      out_g[(mbase + m) * DOUT + o] = s;
    }
  }
}

extern "C" void kernel_launch(void* const* d_in, const int* in_sizes, int n_in,
                              void* d_out, int out_size, void* d_ws, size_t ws_size,
                              hipStream_t stream) {
  const float* x = (const float*)d_in[0];
  const float* W = (const float*)d_in[1];
  const float* b = (const float*)d_in[2];
  const float* Wf = (const float*)d_in[3];
  const float* bf = (const float*)d_in[4];
  float* out = (float*)d_out;

  const size_t need = (size_t)N_LAYERS * 2 * LCHUNK;          // 28.672 MB (hi only)
  const int nwg = 65536 / TM;                                 // 1024
  if (ws_size >= need) {
    char* whi = (char*)d_ws;
    const int chunks = N_LAYERS * 2 * 7 * 2 * 64;             // 1,792,000
    presplit_kernel<<<(chunks + 255) / 256, 256, 0, stream>>>(W, b, whi);
    (void)hipFuncSetAttribute(reinterpret_cast<const void*>(resnet_main<1>),
                              hipFuncAttributeMaxDynamicSharedMemorySize, SMEM_BYTES);
    resnet_main<1><<<nwg, 256, SMEM_BYTES, stream>>>(x, W, b, Wf, bf, out, whi);
  } else {
    (void)hipFuncSetAttribute(reinterpret_cast<const void*>(resnet_main<0>),
                              hipFuncAttributeMaxDynamicSharedMemorySize, SMEM_BYTES);
    resnet_main<0><<<nwg, 256, SMEM_BYTES, stream>>>(x, W, b, Wf, bf, out, nullptr);
  }
}

// Round 15
// 2220.020 us; speedup vs baseline: 6.8163x; 6.8163x over previous
//
#include <hip/hip_runtime.h>
#include <hip/hip_bf16.h>

#define N_LAYERS 1000
#define DD 100
#define DOUT 10
#define TM 64
#define ROWB 264                  // act row stride bytes: 66 words = 2 mod 32 -> 2-way banks (free)
#define PLANE (TM * ROWB)         // 16896 B = one act buffer (single bf16 plane)
#define SMEM_BYTES (2 * PLANE)    // double-buffered: 33792 B -> 4 wgs/CU
#define ROW32 (32 * ROWB)         // 8448: +1 m-tile offset, compile-time immediate
#define LCHUNK 14336              // packed W bytes per (layer, group)
#define LSTRIDE (2 * LCHUNK)      // 28672 B per layer

typedef short s4v __attribute__((ext_vector_type(4)));
typedef short s8v __attribute__((ext_vector_type(8)));
typedef float f16v __attribute__((ext_vector_type(16)));

__device__ __forceinline__ unsigned short f2bf(float f) {
  __hip_bfloat16 h = __float2bfloat16(f);   // HW RNE
  return *reinterpret_cast<unsigned short*>(&h);
}
__device__ __forceinline__ float bf2f(unsigned short h) {
  return __uint_as_float(((unsigned)h) << 16);
}

// ---------------- prologue: W (f32) + bias -> lane-packed bf16 fragments (hi only) ----------
// byte off = (L*2+g)*LCHUNK + ks*2048 + f*1024 + lane*16
// frag: n = g*64+f*32+(lane&31), k = ks*16+(lane>>5)*8+j ; k==100 holds bias; pads zero.
__global__ __launch_bounds__(256)
void presplit_kernel(const float* __restrict__ W, const float* __restrict__ b,
                     char* __restrict__ hi_g) {
  int idx = blockIdx.x * 256 + threadIdx.x;
  if (idx >= N_LAYERS * 2 * 7 * 2 * 64) return;
  int lane = idx & 63;
  int f = (idx >> 6) & 1;
  int r = idx >> 7;
  int ks = r % 7;
  int q = r / 7;
  int g = q & 1;
  int L = q >> 1;
  int n = g * 64 + f * 32 + (lane & 31);
  int k0 = ks * 16 + (lane >> 5) * 8;
  s8v hv;
#pragma unroll
  for (int j = 0; j < 8; ++j) {
    int k = k0 + j;
    float v = 0.0f;
    if (n < DD) {
      if (k < DD) v = W[((size_t)L * DD + n) * DD + k];
      else if (k == DD) v = b[(size_t)L * DD + n];
    }
    hv[j] = (short)f2bf(v);
  }
  *(s8v*)(hi_g + (size_t)idx * 16) = hv;
}

// fallback W gather from raw f32 (one 32-channel fragment; used when d_ws too small)
__device__ __forceinline__ void wload_f32(s8v& h, int L, int ks, int nb,
                                          int l31, int lhi,
                                          const float* __restrict__ W_g,
                                          const float* __restrict__ b_g) {
  int n = nb + l31;
  int k0 = ks * 16 + lhi * 8;
  s8v hv;
#pragma unroll
  for (int j = 0; j < 8; ++j) {
    int k = k0 + j;
    float v = 0.0f;
    if (n < DD) {
      if (k < DD) v = W_g[((size_t)L * DD + n) * DD + k];
      else if (k == DD) v = b_g[(size_t)L * DD + n];
    }
    hv[j] = (short)f2bf(v);
  }
  h = hv;
}

// ---------------- one layer: depth-2 W slots (r12-proven schedule), minimal reg state ------
template <int PRE>
__device__ __forceinline__ void do_layer(
    int L, const char* __restrict__ rb, char* __restrict__ wb,
    int nb, int l31, int lhi,
    const char* __restrict__ pH, int woff,
    s8v (&wh)[2], f16v (&xr)[2],
    const float* __restrict__ W_g, const float* __restrict__ b_g) {
  f16v acc[2];
#pragma unroll
  for (int mi = 0; mi < 2; ++mi)
#pragma unroll
    for (int r = 0; r < 16; ++r) acc[mi][r] = 0.0f;

#pragma unroll
  for (int ks = 0; ks < 7; ++ks) {
    const int s = ks & 1;
    s4v a0 = *(const s4v*)(rb + ks * 32);
    s4v a1 = *(const s4v*)(rb + ks * 32 + 8);
    s4v b0 = *(const s4v*)(rb + ROW32 + ks * 32);
    s4v b1 = *(const s4v*)(rb + ROW32 + ks * 32 + 8);
    s8v ah0 = __builtin_shufflevector(a0, a1, 0, 1, 2, 3, 4, 5, 6, 7);
    s8v ah1 = __builtin_shufflevector(b0, b1, 0, 1, 2, 3, 4, 5, 6, 7);
    acc[0] = __builtin_amdgcn_mfma_f32_32x32x16_bf16(wh[s], ah0, acc[0], 0, 0, 0);
    acc[1] = __builtin_amdgcn_mfma_f32_32x32x16_bf16(wh[s], ah1, acc[1], 0, 0, 0);

    // depth-2 prefetch; cross-layer refill at ks==6 (r12-proven schedule)
    if (ks < 5) {
      if (PRE) wh[s] = *(const s8v*)(pH + woff + (ks + 2) * 2048);
      else     wload_f32(wh[s], L, ks + 2, nb, l31, lhi, W_g, b_g);
    } else if (ks == 6 && L + 1 < N_LAYERS) {
      if (PRE) {
        wh[0] = *(const s8v*)(pH + woff + LSTRIDE);
        wh[1] = *(const s8v*)(pH + woff + LSTRIDE + 2048);
      } else {
        wload_f32(wh[0], L + 1, 0, nb, l31, lhi, W_g, b_g);
        wload_f32(wh[1], L + 1, 1, nb, l31, lhi, W_g, b_g);
      }
    }
  }

  // ---- epilogue: relu (+residual at block end), cast bf16, write both m-tiles ----
  const bool bend = ((L % 10) == 9);
#pragma unroll
  for (int mi = 0; mi < 2; ++mi) {
    char* dstm = wb + mi * ROW32;
#pragma unroll
    for (int q = 0; q < 4; ++q) {
      const int n0 = nb + 8 * q + 4 * lhi;
      char* dst = dstm + q * 16;
      if (n0 == 100) {   // bias column: act[100]=1.0, pads 101..103 = 0
        s4v hq;
        hq[0] = (short)0x3F80; hq[1] = 0; hq[2] = 0; hq[3] = 0;
        *(s4v*)dst = hq;
      } else {
        s4v hq;
#pragma unroll
        for (int j = 0; j < 4; ++j) {
          const int r = q * 4 + j;
          float o = fmaxf(acc[mi][r], 0.0f);
          if (bend) { o += xr[mi][r]; xr[mi][r] = o; }   // exact f32 stream carrier
          hq[j] = (short)f2bf(o);
        }
        *(s4v*)dst = hq;
      }
    }
  }
  __syncthreads();   // single barrier per layer (double buffer)
}

// ---------------- main kernel: 1024 wgs x 256 thr, 4 wgs/CU = 16 waves/CU (4/SIMD) --------
// wg = 64 batch rows, 4 waves. Wave wv owns channels [wv*32, wv*32+32) x all 64 rows
// (2 m-tiles): disjoint W f-half fragments -> zero W duplication per CU.
// Register budget at 4 waves/SIMD = 128 unified (64 arch / 64 acc rigid split):
// acc-side = acc(32)+xr(32) = 64 exactly; arch-side = wh(8)+ah(8)+temps ~45 < 64.
template <int PRE>
__global__ __launch_bounds__(256, 4)
void resnet_main(const float* __restrict__ x_g,
                 const float* __restrict__ W_g, const float* __restrict__ b_g,
                 const float* __restrict__ Wf_g, const float* __restrict__ bf_g,
                 float* __restrict__ out_g,
                 const char* __restrict__ whi_g) {
  extern __shared__ char smem[];

  const int tid = threadIdx.x;
  const int lane = tid & 63;
  const int wv = tid >> 6;         // wave 0..3
  const int nb = wv * 32;          // wave's channel base
  const int l31 = lane & 31;
  const int lhi = lane >> 5;
  const size_t mbase = (size_t)blockIdx.x * TM;

  // ---- initial activation staging into buf A: bf16(x); k==100 -> 1.0; k>100 -> 0 ----
  for (int idx = tid; idx < TM * 16; idx += 256) {
    int m = idx >> 4, kb = idx & 15;
    s4v h0, h1;
#pragma unroll
    for (int j = 0; j < 8; ++j) {
      int k = kb * 8 + j;
      float v = (k < DD) ? x_g[(mbase + m) * DD + k] : (k == DD ? 1.0f : 0.0f);
      if (j < 4) h0[j] = (short)f2bf(v);
      else       h1[j - 4] = (short)f2bf(v);
    }
    char* p = smem + m * ROWB + kb * 16;
    *(s4v*)p = h0;
    *(s4v*)(p + 8) = h1;
  }

  // ---- residual: block input in f32 registers, C-fragment layout (2 m-tiles) ----
  f16v xr[2];
#pragma unroll
  for (int mi = 0; mi < 2; ++mi)
#pragma unroll
    for (int r = 0; r < 16; ++r) {
      int n = nb + (r & 3) + 8 * (r >> 2) + 4 * lhi;
      xr[mi][r] = (n < DD) ? x_g[(mbase + mi * 32 + l31) * DD + n] : 0.0f;
    }

  // ---- depth-2 W register pipeline: preload ks=0,1 of layer 0 (this wave's f-half) ----
  const char* pH = whi_g + (size_t)(wv >> 1) * LCHUNK + (wv & 1) * 1024 + lane * 16;
  s8v wh[2];
  if (PRE) {
    wh[0] = *(const s8v*)(pH);
    wh[1] = *(const s8v*)(pH + 2048);
  } else {
    wload_f32(wh[0], 0, 0, nb, l31, lhi, W_g, b_g);
    wload_f32(wh[1], 0, 1, nb, l31, lhi, W_g, b_g);
  }

  __syncthreads();

  // buffer A = smem, buffer B = smem + PLANE; layer L reads buf[L&1], writes buf[~L&1]
  const char* rbA = smem + l31 * ROWB + lhi * 16;
  const char* rbB = rbA + PLANE;
  char* wbA = smem + l31 * ROWB + nb * 2 + lhi * 8;
  char* wbB = wbA + PLANE;

  int woff = 0;
  for (int L = 0; L < N_LAYERS; L += 2) {
    do_layer<PRE>(L,     rbA, wbB, nb, l31, lhi, pH, woff,           wh, xr, W_g, b_g);
    do_layer<PRE>(L + 1, rbB, wbA, nb, l31, lhi, pH, woff + LSTRIDE, wh, xr, W_g, b_g);
    woff += 2 * LSTRIDE;
  }

  // ---- final projection: out = act @ Wf^T + bf  (act = buf A after layer 999) ----
  if (tid < TM) {
    int m = tid;
    const char* p = smem + m * ROWB;
    float xv[104];
#pragma unroll
    for (int kb = 0; kb < 13; ++kb) {
      s4v h0 = *(const s4v*)(p + kb * 16);
      s4v h1 = *(const s4v*)(p + kb * 16 + 8);
#pragma unroll
      for (int j = 0; j < 4; ++j) {
        xv[kb * 8 + j]     = bf2f((unsigned short)h0[j]);
        xv[kb * 8 + 4 + j] = bf2f((unsigned short)h1[j]);
      }
    }
#pragma unroll
    for (int o = 0; o < DOUT; ++o) {
      float s = bf_g[o];
#pragma unroll
      for (int k = 0; k < DD; ++k) s += xv[k] * Wf_g[o * DD + k];
      out_g[(mbase + m) * DOUT + o] = s;
    }
  }
}

extern "C" void kernel_launch(void* const* d_in, const int* in_sizes, int n_in,
                              void* d_out, int out_size, void* d_ws, size_t ws_size,
                              hipStream_t stream) {
  const float* x = (const float*)d_in[0];
  const float* W = (const float*)d_in[1];
  const float* b = (const float*)d_in[2];
  const float* Wf = (const float*)d_in[3];
  const float* bf = (const float*)d_in[4];
  float* out = (float*)d_out;

  const size_t need = (size_t)N_LAYERS * 2 * LCHUNK;          // 28.672 MB (hi only)
  const int nwg = 65536 / TM;                                 // 1024
  if (ws_size >= need) {
    char* whi = (char*)d_ws;
    const int chunks = N_LAYERS * 2 * 7 * 2 * 64;             // 1,792,000
    presplit_kernel<<<(chunks + 255) / 256, 256, 0, stream>>>(W, b, whi);
    (void)hipFuncSetAttribute(reinterpret_cast<const void*>(resnet_main<1>),
                              hipFuncAttributeMaxDynamicSharedMemorySize, SMEM_BYTES);
    resnet_main<1><<<nwg, 256, SMEM_BYTES, stream>>>(x, W, b, Wf, bf, out, whi);
  } else {
    (void)hipFuncSetAttribute(reinterpret_cast<const void*>(resnet_main<0>),
                              hipFuncAttributeMaxDynamicSharedMemorySize, SMEM_BYTES);
    resnet_main<0><<<nwg, 256, SMEM_BYTES, stream>>>(x, W, b, Wf, bf, out, nullptr);
  }
}